// Round 5
// baseline (119.699 us; speedup 1.0000x reference)
//
#include <hip/hip_runtime.h>
#include <cstdint>

typedef unsigned short u16;
typedef __attribute__((ext_vector_type(8))) __bf16 bf16x8;
typedef __attribute__((ext_vector_type(4))) float f32x4;

#define NROWS 8192
#define KDIM  256
#define TILE  128
#define TPB   8   // col tiles per block

__device__ __forceinline__ u16 f2bf(float f) {
  uint32_t u = __builtin_bit_cast(uint32_t, f);
  return (u16)((u + 0x7fffu + ((u >> 16) & 1u)) >> 16);
}

// One wave per row: convert f32 row (256 elems) to bf16 (RNE) and compute sum of squares.
__global__ void __launch_bounds__(256) prep_kernel(const float* __restrict__ src,
                                                   u16* __restrict__ dst,
                                                   float* __restrict__ norms) {
  const int row  = blockIdx.x * 4 + (threadIdx.x >> 6);
  const int lane = threadIdx.x & 63;
  const float4 v = *reinterpret_cast<const float4*>(&src[row * KDIM + lane * 4]);
  float s = v.x * v.x + v.y * v.y + v.z * v.z + v.w * v.w;
#pragma unroll
  for (int off = 32; off > 0; off >>= 1) s += __shfl_down(s, off, 64);
  ushort4 b;
  b.x = f2bf(v.x); b.y = f2bf(v.y); b.z = f2bf(v.z); b.w = f2bf(v.w);
  *reinterpret_cast<ushort4*>(&dst[row * KDIM + lane * 4]) = b;
  if (lane == 0) norms[row] = s;
}

// Stage a 128x256 bf16 B-panel into LDS with a bank-conflict-free swizzle.
// LDS layout: byte(row, c) = row*512 + (c&15) + 16*((c>>4) ^ swz(row)),
// swz(row) = (row&15) | ((row&1)<<4). global_load_lds writes linearly
// (base + lane*16), so we pre-swizzle the GLOBAL source slot instead (rule #21).
__device__ __forceinline__ void stageB(u16* sB, const u16* __restrict__ Bbase, int tid) {
  const int wave = tid >> 6;
#pragma unroll
  for (int it = 0; it < 16; ++it) {
    const int row = it * 8 + (tid >> 5);
    const int swz = (row & 15) | ((row & 1) << 4);
    const int srcSlot = (tid & 31) ^ swz;   // 0..31, bijective per row
    __builtin_amdgcn_global_load_lds(
        (const __attribute__((address_space(1))) void*)&Bbase[(size_t)row * KDIM + srcSlot * 8],
        (__attribute__((address_space(3))) void*)&sB[it * 2048 + wave * 512],
        16, 0, 0);
  }
}

// 512 blocks; block = (rowPanel = b>>3, colGroup = b&7). Each block: A-panel rows
// [rowPanel*128, +128) held in REGISTERS (af[4][8] per wave, 128 VGPR), loops over
// 8 col-tiles of the colGroup. Per tile: B-panel staged to LDS (swizzled), 128
// MFMAs, fused epilogue. stage(t+1) is issued under epilogue(t) so write drain,
// staging and compute pipeline across tiles. colGroup==XCD (b%8) -> B panels are
// XCD-private (L2 hits after first block touches them).
// SWAPPED-OPERAND MFMA: acc = mfma(bfr, af) => lane holds out row = lane&15,
// out cols = (lane>>4)*4 + reg -> float4 stores.
// SENTINEL: must not be -inf (diff NaN) and must stay finite under bf16 RNE
// (-FLT_MAX rounds to -inf in bf16); -3.0e38 is safe.
__global__ void __launch_bounds__(256, 1) gemm_mask_kernel(const u16* __restrict__ A,
                                                           const u16* __restrict__ B,
                                                           const float* __restrict__ x2,
                                                           const float* __restrict__ y2,
                                                           float* __restrict__ out) {
  __shared__ __align__(16) u16 sB[TILE * KDIM];   // 64 KB
  const int tid  = threadIdx.x;
  const int wave = tid >> 6;
  const int lane = tid & 63;
  const int lo = lane & 15, hi = lane >> 4;
  const int wr = wave >> 1, wc = wave & 1;
  const int rowPanel = blockIdx.x >> 3;
  const int colGroup = blockIdx.x & 7;
  const int rowBase  = rowPanel * TILE;

  // Issue first B-panel stage, then overlap A-frag register loads under it.
  stageB(sB, B + (size_t)(colGroup * TPB) * TILE * KDIM, tid);

  bf16x8 af[4][8];   // rows wr*64 + m*16 + lo, k-slices ks*32 + hi*8
#pragma unroll
  for (int m = 0; m < 4; ++m) {
    const u16* arow = A + (size_t)(rowBase + wr * 64 + m * 16 + lo) * KDIM;
#pragma unroll
    for (int ks = 0; ks < 8; ++ks)
      af[m][ks] = *reinterpret_cast<const bf16x8*>(&arow[ks * 32 + hi * 8]);
  }
  __syncthreads();   // drains vmcnt: B(0) in LDS, af in VGPRs

  for (int t = 0; t < TPB; ++t) {
    const int colTile = colGroup * TPB + t;
    const int colBase = colTile * TILE;

    f32x4 acc[4][4] = {};
#pragma unroll
    for (int ks = 0; ks < 8; ++ks) {
      bf16x8 bfr[4];
#pragma unroll
      for (int n = 0; n < 4; ++n) {
        const int row  = wc * 64 + n * 16 + lo;
        const int slot = (ks * 4 + hi) ^ ((row & 15) | ((row & 1) << 4));
        bfr[n] = *reinterpret_cast<const bf16x8*>(&sB[row * KDIM + slot * 8]);
      }
#pragma unroll
      for (int m = 0; m < 4; ++m)
#pragma unroll
        for (int n = 0; n < 4; ++n)
          acc[m][n] = __builtin_amdgcn_mfma_f32_16x16x32_bf16(bfr[n], af[m][ks], acc[m][n], 0, 0, 0);
    }
    __syncthreads();                 // all waves done reading sB
    if (t + 1 < TPB)
      stageB(sB, B + (size_t)(colTile + 1) * TILE * KDIM, tid);   // issue under epilogue

    // Fused epilogue: d2 = x2+y2-2*dot; out = d2>64 ? SENT : -sqrt(d2).
    const float SENT = -3.0e38f;
    float4 yv[4];
#pragma unroll
    for (int n = 0; n < 4; ++n)
      yv[n] = *reinterpret_cast<const float4*>(&y2[colBase + wc * 64 + n * 16 + hi * 4]);
#pragma unroll
    for (int m = 0; m < 4; ++m) {
      const int row  = rowBase + wr * 64 + m * 16 + lo;
      const float xr = x2[row];
      float* orow = out + (size_t)row * NROWS + colBase + wc * 64 + hi * 4;
#pragma unroll
      for (int n = 0; n < 4; ++n) {
        float4 o;
        {
          float d2 = fmaxf(xr + yv[n].x - 2.0f * acc[m][n][0], 0.0f);
          o.x = (d2 > 64.0f) ? SENT : -__builtin_sqrtf(d2);
        }
        {
          float d2 = fmaxf(xr + yv[n].y - 2.0f * acc[m][n][1], 0.0f);
          o.y = (d2 > 64.0f) ? SENT : -__builtin_sqrtf(d2);
        }
        {
          float d2 = fmaxf(xr + yv[n].z - 2.0f * acc[m][n][2], 0.0f);
          o.z = (d2 > 64.0f) ? SENT : -__builtin_sqrtf(d2);
        }
        {
          float d2 = fmaxf(xr + yv[n].w - 2.0f * acc[m][n][3], 0.0f);
          o.w = (d2 > 64.0f) ? SENT : -__builtin_sqrtf(d2);
        }
        *reinterpret_cast<float4*>(&orow[n * 16]) = o;
      }
    }
    if (t + 1 < TPB) __syncthreads();   // B(t+1) landed
  }
}

extern "C" void kernel_launch(void* const* d_in, const int* in_sizes, int n_in,
                              void* d_out, int out_size, void* d_ws, size_t ws_size,
                              hipStream_t stream) {
  const float* x  = (const float*)d_in[0];
  const float* xn = (const float*)d_in[1];
  float* out = (float*)d_out;

  // Workspace: bf16 X (4MB) | bf16 Xn (4MB) | x2 (32KB) | y2 (32KB)
  u16* Xb = (u16*)d_ws;
  u16* Yb = Xb + (size_t)NROWS * KDIM;
  float* x2 = (float*)(Yb + (size_t)NROWS * KDIM);
  float* y2 = x2 + NROWS;

  prep_kernel<<<NROWS / 4, 256, 0, stream>>>(x, Xb, x2);
  prep_kernel<<<NROWS / 4, 256, 0, stream>>>(xn, Yb, y2);
  gemm_mask_kernel<<<dim3(512), dim3(256), 0, stream>>>(Xb, Yb, x2, y2, out);
}